// Round 10
// baseline (208.765 us; speedup 1.0000x reference)
//
#include <hip/hip_runtime.h>

#define NUM_NODES 100000
#define IN_F 256
#define OUT_F 128
#define TILE 128
#define NT ((NUM_NODES + TILE - 1) / TILE)   // 782 tiles of 128 nodes
#define NSG 98               // supergroups of 1024 nodes (8 tiles)
#define CHUNK1 2048
#define CAP1 20480           // per-supergroup capacity (mean 16327, ~32 sigma)
#define CAP 2560             // per-tile srow capacity (mean 2046, 11 sigma)

typedef __attribute__((ext_vector_type(8))) short bf16x8;
typedef __attribute__((ext_vector_type(4))) float f32x4;

// bf16 round-to-nearest-even of one float.
__device__ inline unsigned short f2bf(float f) {
    unsigned u = __float_as_uint(f);
    u = (u + 0x7FFFu + ((u >> 16) & 1u)) >> 16;
    return (unsigned short)u;
}
__device__ inline float bf_lo(unsigned int u) { return __uint_as_float(u << 16); }
__device__ inline float bf_hi(unsigned int u) { return __uint_as_float(u & 0xFFFF0000u); }

// ---------------------------------------------------------------------------
// WT[n][k] = bf16(W[k][n])
// ---------------------------------------------------------------------------
__global__ __launch_bounds__(256) void convert_wt_kernel(
    const float* __restrict__ w, unsigned short* __restrict__ wt)
{
    int g = blockIdx.x * 256 + threadIdx.x;      // 0..32767 = k*128+n
    int k = g >> 7, n = g & 127;
    wt[n * 256 + k] = f2bf(w[g]);
}

// ---------------------------------------------------------------------------
// support = bf16(X @ W) via MFMA. 8 waves x 16-row strips = 128 rows/block.
// (unchanged — verified; ~its memory floor)
// ---------------------------------------------------------------------------
__global__ __launch_bounds__(512) void gemm_mfma_kernel(
    const float* __restrict__ x, const unsigned short* __restrict__ wt,
    unsigned short* __restrict__ support_h)
{
    __shared__ unsigned short WT[128][264];

    const int tid = threadIdx.x;
    const uint4* src = reinterpret_cast<const uint4*>(wt);
#pragma unroll
    for (int i = 0; i < 8; ++i) {
        int j = tid + i * 512;
        int r = j >> 5;
        int c = (j & 31) << 3;
        *reinterpret_cast<uint4*>(&WT[r][c]) = src[j];
    }
    __syncthreads();

    const int wave = tid >> 6;
    const int lane = tid & 63;
    const int q = lane >> 4;
    const int r16 = lane & 15;
    const int strip_row = blockIdx.x * 128 + wave * 16;

    int arow = strip_row + r16;
    if (arow >= NUM_NODES) arow = NUM_NODES - 1;
    const float* xrow = x + (size_t)arow * IN_F + q * 8;

    f32x4 acc[8];
#pragma unroll
    for (int n = 0; n < 8; ++n) acc[n] = (f32x4){0.f, 0.f, 0.f, 0.f};

#pragma unroll
    for (int half = 0; half < 2; ++half) {
        float4 a[8];
#pragma unroll
        for (int g = 0; g < 4; ++g) {
            const float* p = xrow + half * 128 + g * 32;
            a[g * 2]     = *reinterpret_cast<const float4*>(p);
            a[g * 2 + 1] = *reinterpret_cast<const float4*>(p + 4);
        }
#pragma unroll
        for (int g = 0; g < 4; ++g) {
            const int k0 = half * 128 + g * 32;
            bf16x8 af;
            af[0] = (short)f2bf(a[g * 2].x);
            af[1] = (short)f2bf(a[g * 2].y);
            af[2] = (short)f2bf(a[g * 2].z);
            af[3] = (short)f2bf(a[g * 2].w);
            af[4] = (short)f2bf(a[g * 2 + 1].x);
            af[5] = (short)f2bf(a[g * 2 + 1].y);
            af[6] = (short)f2bf(a[g * 2 + 1].z);
            af[7] = (short)f2bf(a[g * 2 + 1].w);
#pragma unroll
            for (int n = 0; n < 8; ++n) {
                bf16x8 bfr = *reinterpret_cast<const bf16x8*>(
                    &WT[n * 16 + r16][k0 + q * 8]);
                acc[n] = __builtin_amdgcn_mfma_f32_16x16x32_bf16(
                    af, bfr, acc[n], 0, 0, 0);
            }
        }
    }

#pragma unroll
    for (int n = 0; n < 8; ++n) {
#pragma unroll
        for (int rr = 0; rr < 4; ++rr) {
            int grow = strip_row + q * 4 + rr;
            if (grow < NUM_NODES)
                support_h[(size_t)grow * OUT_F + n * 16 + r16] = f2bf(acc[n][rr]);
        }
    }
}

// ---------------------------------------------------------------------------
// Single radix pass: split edges into 98 supergroup regions (1024 dest
// nodes). chunk 2048 (782 blocks -> ~3/CU), wave-0 shfl scan (2 barriers).
// rec = (row << 10) | (col & 1023).
// ---------------------------------------------------------------------------
__global__ __launch_bounds__(256) void sg_split_kernel(
    const int* __restrict__ ei, int E, int* __restrict__ gcur1,
    unsigned int* __restrict__ g1rec)
{
    __shared__ int hist[128], base[128], gbase[128], cur[128];
    __shared__ unsigned int sorted[CHUNK1];
    const int t = threadIdx.x;
    const int lane = t & 63;
    const int wid = t >> 6;
    const int e0 = blockIdx.x * CHUNK1;

    if (t < 128) hist[t] = 0;
    __syncthreads();

#pragma unroll
    for (int i = 0; i < CHUNK1 / 256; ++i) {
        int e = e0 + i * 256 + t;
        if (e < E) atomicAdd(&hist[ei[E + e] >> 10], 1);
    }
    __syncthreads();

    // wave-0 shfl exclusive scan of hist[128] + global reservations
    if (wid == 0) {
        int h0 = hist[2 * lane];
        int h1 = hist[2 * lane + 1];
        int s = h0 + h1;
        int sc = s;
#pragma unroll
        for (int d = 1; d < 64; d <<= 1) {
            int t2 = __shfl_up(sc, d);
            if (lane >= d) sc += t2;
        }
        int ex = sc - s;
        base[2 * lane]     = ex;      cur[2 * lane]     = ex;
        base[2 * lane + 1] = ex + h0; cur[2 * lane + 1] = ex + h0;
        gbase[2 * lane]     = h0 ? atomicAdd(&gcur1[2 * lane], h0) : 0;
        gbase[2 * lane + 1] = h1 ? atomicAdd(&gcur1[2 * lane + 1], h1) : 0;
    }
    __syncthreads();

#pragma unroll
    for (int i = 0; i < CHUNK1 / 256; ++i) {
        int e = e0 + i * 256 + t;
        if (e < E) {
            int row = ei[e], col = ei[E + e];
            int b = col >> 10;
            int pos = atomicAdd(&cur[b], 1);
            sorted[pos] = ((unsigned)row << 10) | (unsigned)(col & 1023);
        }
    }
    __syncthreads();

    for (int b = wid; b < NSG; b += 4) {
        int n = hist[b];
        if (!n) continue;
        int gb = gbase[b], bb = base[b];
        for (int j = lane; j < n; j += 64) {
            int dst = gb + j;
            if (dst < CAP1)
                g1rec[(size_t)b * CAP1 + dst] = sorted[bb + j];
        }
    }
}

// ---------------------------------------------------------------------------
// Fused filter + per-tile counting-sort + register-accumulate aggregate.
// 1 block (512 thr) per 128-node tile t; sg = t>>3, sub-tile s = t&7.
// Scans the supergroup's record region twice (hist pass, scatter pass)
// filtering (r>>7)&7 == s (L2-resident broadcast reads), then accumulates
// node-grouped runs with 16-deep gather batches into 32 VGPR fp32 accs.
// No fp atomics. Epilogue: out = acc + support_self + bias.
// ---------------------------------------------------------------------------
__global__ __launch_bounds__(512) void tile_sort_agg_kernel(
    const unsigned int* __restrict__ support_bf,
    const unsigned int* __restrict__ g1rec,
    const int* __restrict__ gcur1,
    const float* __restrict__ bias,
    float* __restrict__ out)
{
    __shared__ int srow[CAP];
    __shared__ int hist[128], off[128], cur[128];

    const int tid = threadIdx.x;
    const int lane = tid & 63;
    const int wid = tid >> 6;
    const int tile = blockIdx.x;
    const int sg = tile >> 3;
    const unsigned int s = tile & 7;
    const int node0 = tile << 7;

    float accx[16], accy[16];
#pragma unroll
    for (int li = 0; li < 16; ++li) { accx[li] = 0.f; accy[li] = 0.f; }

    int cnt1 = gcur1[sg];
    if (cnt1 > CAP1) cnt1 = CAP1;
    const unsigned int* g1 = g1rec + (size_t)sg * CAP1;

    if (tid < 128) hist[tid] = 0;
    __syncthreads();

    // Pass A: filtered histogram over this tile's nodes
    for (int i = tid; i < cnt1; i += 512) {
        unsigned r = g1[i];
        if (((r >> 7) & 7u) == s) atomicAdd(&hist[r & 127], 1);
    }
    __syncthreads();

    // wave-0 shfl exclusive scan of hist[128]
    if (wid == 0) {
        int h0 = hist[2 * lane];
        int h1 = hist[2 * lane + 1];
        int sm = h0 + h1;
        int sc = sm;
#pragma unroll
        for (int d = 1; d < 64; d <<= 1) {
            int t2 = __shfl_up(sc, d);
            if (lane >= d) sc += t2;
        }
        int ex = sc - sm;
        off[2 * lane]     = ex;      cur[2 * lane]     = ex;
        off[2 * lane + 1] = ex + h0; cur[2 * lane + 1] = ex + h0;
    }
    __syncthreads();

    // Pass B: filtered scatter of source rows into node-grouped runs
    for (int i = tid; i < cnt1; i += 512) {
        unsigned r = g1[i];
        if (((r >> 7) & 7u) == s) {
            int pos = atomicAdd(&cur[r & 127], 1);
            if (pos < CAP) srow[pos] = (int)(r >> 10);
        }
    }
    __syncthreads();

    // accumulate: wave w owns local nodes w, 8+w, ..., 120+w (16-deep MLP)
#pragma unroll
    for (int li = 0; li < 16; ++li) {
        const int c = li * 8 + wid;
        int j = off[c];
        const int jend = j + hist[c];
        float ax = accx[li], ay = accy[li];
        for (; j + 15 < jend; j += 16) {
            int r0 = srow[j],      r1 = srow[j + 1];
            int r2 = srow[j + 2],  r3 = srow[j + 3];
            int r4 = srow[j + 4],  r5 = srow[j + 5];
            int r6 = srow[j + 6],  r7 = srow[j + 7];
            int r8 = srow[j + 8],  r9 = srow[j + 9];
            int rA = srow[j + 10], rB = srow[j + 11];
            int rC = srow[j + 12], rD = srow[j + 13];
            int rE = srow[j + 14], rF = srow[j + 15];
            unsigned u0 = support_bf[(size_t)r0 * 64 + lane];
            unsigned u1 = support_bf[(size_t)r1 * 64 + lane];
            unsigned u2 = support_bf[(size_t)r2 * 64 + lane];
            unsigned u3 = support_bf[(size_t)r3 * 64 + lane];
            unsigned u4 = support_bf[(size_t)r4 * 64 + lane];
            unsigned u5 = support_bf[(size_t)r5 * 64 + lane];
            unsigned u6 = support_bf[(size_t)r6 * 64 + lane];
            unsigned u7 = support_bf[(size_t)r7 * 64 + lane];
            unsigned u8 = support_bf[(size_t)r8 * 64 + lane];
            unsigned u9 = support_bf[(size_t)r9 * 64 + lane];
            unsigned uA = support_bf[(size_t)rA * 64 + lane];
            unsigned uB = support_bf[(size_t)rB * 64 + lane];
            unsigned uC = support_bf[(size_t)rC * 64 + lane];
            unsigned uD = support_bf[(size_t)rD * 64 + lane];
            unsigned uE = support_bf[(size_t)rE * 64 + lane];
            unsigned uF = support_bf[(size_t)rF * 64 + lane];
            ax += bf_lo(u0); ay += bf_hi(u0);
            ax += bf_lo(u1); ay += bf_hi(u1);
            ax += bf_lo(u2); ay += bf_hi(u2);
            ax += bf_lo(u3); ay += bf_hi(u3);
            ax += bf_lo(u4); ay += bf_hi(u4);
            ax += bf_lo(u5); ay += bf_hi(u5);
            ax += bf_lo(u6); ay += bf_hi(u6);
            ax += bf_lo(u7); ay += bf_hi(u7);
            ax += bf_lo(u8); ay += bf_hi(u8);
            ax += bf_lo(u9); ay += bf_hi(u9);
            ax += bf_lo(uA); ay += bf_hi(uA);
            ax += bf_lo(uB); ay += bf_hi(uB);
            ax += bf_lo(uC); ay += bf_hi(uC);
            ax += bf_lo(uD); ay += bf_hi(uD);
            ax += bf_lo(uE); ay += bf_hi(uE);
            ax += bf_lo(uF); ay += bf_hi(uF);
        }
        for (; j + 3 < jend; j += 4) {
            int r0 = srow[j],     r1 = srow[j + 1];
            int r2 = srow[j + 2], r3 = srow[j + 3];
            unsigned u0 = support_bf[(size_t)r0 * 64 + lane];
            unsigned u1 = support_bf[(size_t)r1 * 64 + lane];
            unsigned u2 = support_bf[(size_t)r2 * 64 + lane];
            unsigned u3 = support_bf[(size_t)r3 * 64 + lane];
            ax += bf_lo(u0); ay += bf_hi(u0);
            ax += bf_lo(u1); ay += bf_hi(u1);
            ax += bf_lo(u2); ay += bf_hi(u2);
            ax += bf_lo(u3); ay += bf_hi(u3);
        }
        for (; j < jend; ++j) {
            unsigned u0 = support_bf[(size_t)srow[j] * 64 + lane];
            ax += bf_lo(u0); ay += bf_hi(u0);
        }
        accx[li] = ax; accy[li] = ay;
    }

    // epilogue: self + bias, single coalesced write
    const int nrows = min(TILE, NUM_NODES - node0);
    float2 bi = *reinterpret_cast<const float2*>(bias + lane * 2);
#pragma unroll
    for (int li = 0; li < 16; ++li) {
        const int c = li * 8 + wid;
        if (c < nrows) {
            const int nd = node0 + c;
            unsigned sv = support_bf[(size_t)nd * 64 + lane];
            float2 o = {accx[li] + bf_lo(sv) + bi.x,
                        accy[li] + bf_hi(sv) + bi.y};
            *reinterpret_cast<float2*>(out + (size_t)nd * OUT_F + lane * 2) = o;
        }
    }
}

extern "C" void kernel_launch(void* const* d_in, const int* in_sizes, int n_in,
                              void* d_out, int out_size, void* d_ws, size_t ws_size,
                              hipStream_t stream) {
    const float* x    = (const float*)d_in[0];
    const float* w    = (const float*)d_in[1];
    const float* bias = (const float*)d_in[2];
    const int*   ei   = (const int*)d_in[3];
    float* out = (float*)d_out;
    const int E = in_sizes[3] / 2;
    const int N = NUM_NODES;

    // Workspace layout (~33.7 MB):
    //   support_bf : N*64 uints (bf16x2)   = 25.6 MB
    //   wt_bf      : 128*256 ushorts       = 64 KB
    //   gcur1      : 128 ints  (per supergroup)
    //   g1rec      : NSG*CAP1 uints        = 8.0 MB
    unsigned int* support_bf = (unsigned int*)d_ws;
    unsigned short* wt_bf = (unsigned short*)(support_bf + (size_t)N * 64);
    int* gcur1 = (int*)(wt_bf + 128 * 256);
    unsigned int* g1rec = (unsigned int*)(gcur1 + 128);

    // 1. GEMM: support = bf16(X @ W) via MFMA
    convert_wt_kernel<<<128, 256, 0, stream>>>(w, wt_bf);
    gemm_mfma_kernel<<<(N + 127) / 128, 512, 0, stream>>>(
        x, wt_bf, (unsigned short*)support_bf);

    // 2. Single radix pass: split edges into supergroup regions
    hipMemsetAsync(gcur1, 0, 128 * sizeof(int), stream);
    sg_split_kernel<<<(E + CHUNK1 - 1) / CHUNK1, 256, 0, stream>>>(
        ei, E, gcur1, g1rec);

    // 3. Fused filter + sort + register-accumulate aggregate
    tile_sort_agg_kernel<<<NT, 512, 0, stream>>>(
        support_bf, g1rec, gcur1, bias, out);
}

// Round 11
// 166.803 us; speedup vs baseline: 1.2516x; 1.2516x over previous
//
#include <hip/hip_runtime.h>

#define NUM_NODES 100000
#define IN_F 256
#define OUT_F 128
#define TILE 128
#define NT ((NUM_NODES + TILE - 1) / TILE)   // 782 tiles of 128 nodes
#define NSG 98               // supergroups of 1024 nodes (8 tiles)
#define CHUNK1 2048
#define CHUNK2 4096
#define CAP1 20480           // per-supergroup capacity (mean 16327, ~32 sigma)
#define SUB2 (CAP1 / CHUNK2) // 5 subchunks per supergroup in pass 2
#define CAP 2560             // per-tile record capacity (mean 2046, 11 sigma)

typedef __attribute__((ext_vector_type(8))) short bf16x8;
typedef __attribute__((ext_vector_type(4))) float f32x4;

__device__ inline unsigned short f2bf(float f) {
    unsigned u = __float_as_uint(f);
    u = (u + 0x7FFFu + ((u >> 16) & 1u)) >> 16;
    return (unsigned short)u;
}
__device__ inline float bf_lo(unsigned int u) { return __uint_as_float(u << 16); }
__device__ inline float bf_hi(unsigned int u) { return __uint_as_float(u & 0xFFFF0000u); }

// ---------------------------------------------------------------------------
// WT[n][k] = bf16(W[k][n])
// ---------------------------------------------------------------------------
__global__ __launch_bounds__(256) void convert_wt_kernel(
    const float* __restrict__ w, unsigned short* __restrict__ wt)
{
    int g = blockIdx.x * 256 + threadIdx.x;      // 0..32767 = k*128+n
    int k = g >> 7, n = g & 127;
    wt[n * 256 + k] = f2bf(w[g]);
}

// ---------------------------------------------------------------------------
// Fused K1: role-interleaved blocks.
//   even blocks: support = bf16(X @ W) via MFMA (8 waves x 16-row strips)
//   odd  blocks: radix pass 1 — split 2048 edges into 98 supergroup regions
// The two roles touch disjoint data; interleaving makes them co-resident so
// the latency-bound split hides under the memory-bound GEMM. LDS is a union.
// ---------------------------------------------------------------------------
struct ShmGemm { unsigned short WT[128][264]; };                 // 67584 B
struct ShmSplit {
    int hist[128], base[128], gbase[128], cur[128];              // 2048 B
    unsigned int sorted[CHUNK1];                                 // 8192 B
};
union ShmK1 { ShmGemm g; ShmSplit s; };

__global__ __launch_bounds__(512) void gemm_split_kernel(
    const float* __restrict__ x, const unsigned short* __restrict__ wt,
    unsigned short* __restrict__ support_h,
    const int* __restrict__ ei, int E,
    int* __restrict__ gcur1, unsigned int* __restrict__ g1rec,
    int nG, int nS)
{
    __shared__ ShmK1 shm;
    const int tid = threadIdx.x;
    const int lane = tid & 63;
    const int wid = tid >> 6;

    // role assignment: interleave the first 2*min(nG,nS) blocks
    int bid = blockIdx.x;
    int nmin = nG < nS ? nG : nS;
    int role, idx;
    if (bid < 2 * nmin) { role = bid & 1; idx = bid >> 1; }
    else { role = (nG < nS) ? 1 : 0; idx = bid - 2 * nmin + nmin; }

    if (role == 0) {
        // ----------------- GEMM tile (128 rows) -----------------
        const uint4* src = reinterpret_cast<const uint4*>(wt);
#pragma unroll
        for (int i = 0; i < 8; ++i) {
            int j = tid + i * 512;
            int r = j >> 5;
            int c = (j & 31) << 3;
            *reinterpret_cast<uint4*>(&shm.g.WT[r][c]) = src[j];
        }
        __syncthreads();

        const int q = lane >> 4;
        const int r16 = lane & 15;
        const int strip_row = idx * 128 + wid * 16;

        int arow = strip_row + r16;
        if (arow >= NUM_NODES) arow = NUM_NODES - 1;
        const float* xrow = x + (size_t)arow * IN_F + q * 8;

        f32x4 acc[8];
#pragma unroll
        for (int n = 0; n < 8; ++n) acc[n] = (f32x4){0.f, 0.f, 0.f, 0.f};

#pragma unroll
        for (int half = 0; half < 2; ++half) {
            float4 a[8];
#pragma unroll
            for (int g = 0; g < 4; ++g) {
                const float* p = xrow + half * 128 + g * 32;
                a[g * 2]     = *reinterpret_cast<const float4*>(p);
                a[g * 2 + 1] = *reinterpret_cast<const float4*>(p + 4);
            }
#pragma unroll
            for (int g = 0; g < 4; ++g) {
                const int k0 = half * 128 + g * 32;
                bf16x8 af;
                af[0] = (short)f2bf(a[g * 2].x);
                af[1] = (short)f2bf(a[g * 2].y);
                af[2] = (short)f2bf(a[g * 2].z);
                af[3] = (short)f2bf(a[g * 2].w);
                af[4] = (short)f2bf(a[g * 2 + 1].x);
                af[5] = (short)f2bf(a[g * 2 + 1].y);
                af[6] = (short)f2bf(a[g * 2 + 1].z);
                af[7] = (short)f2bf(a[g * 2 + 1].w);
#pragma unroll
                for (int n = 0; n < 8; ++n) {
                    bf16x8 bfr = *reinterpret_cast<const bf16x8*>(
                        &shm.g.WT[n * 16 + r16][k0 + q * 8]);
                    acc[n] = __builtin_amdgcn_mfma_f32_16x16x32_bf16(
                        af, bfr, acc[n], 0, 0, 0);
                }
            }
        }

#pragma unroll
        for (int n = 0; n < 8; ++n) {
#pragma unroll
            for (int rr = 0; rr < 4; ++rr) {
                int grow = strip_row + q * 4 + rr;
                if (grow < NUM_NODES)
                    support_h[(size_t)grow * OUT_F + n * 16 + r16] =
                        f2bf(acc[n][rr]);
            }
        }
    } else {
        // ----------------- radix pass 1 (2048 edges) -----------------
        const int e0 = idx * CHUNK1;

        if (tid < 128) shm.s.hist[tid] = 0;
        __syncthreads();

#pragma unroll
        for (int i = 0; i < CHUNK1 / 512; ++i) {
            int e = e0 + i * 512 + tid;
            if (e < E) atomicAdd(&shm.s.hist[ei[E + e] >> 10], 1);
        }
        __syncthreads();

        if (wid == 0) {
            int h0 = shm.s.hist[2 * lane];
            int h1 = shm.s.hist[2 * lane + 1];
            int s = h0 + h1;
            int sc = s;
#pragma unroll
            for (int d = 1; d < 64; d <<= 1) {
                int t2 = __shfl_up(sc, d);
                if (lane >= d) sc += t2;
            }
            int ex = sc - s;
            shm.s.base[2 * lane]     = ex;      shm.s.cur[2 * lane]     = ex;
            shm.s.base[2 * lane + 1] = ex + h0; shm.s.cur[2 * lane + 1] = ex + h0;
            shm.s.gbase[2 * lane] =
                h0 ? atomicAdd(&gcur1[2 * lane], h0) : 0;
            shm.s.gbase[2 * lane + 1] =
                h1 ? atomicAdd(&gcur1[2 * lane + 1], h1) : 0;
        }
        __syncthreads();

#pragma unroll
        for (int i = 0; i < CHUNK1 / 512; ++i) {
            int e = e0 + i * 512 + tid;
            if (e < E) {
                int row = ei[e], col = ei[E + e];
                int b = col >> 10;
                int pos = atomicAdd(&shm.s.cur[b], 1);
                shm.s.sorted[pos] =
                    ((unsigned)row << 10) | (unsigned)(col & 1023);
            }
        }
        __syncthreads();

        for (int b = wid; b < NSG; b += 8) {
            int n = shm.s.hist[b];
            if (!n) continue;
            int gb = shm.s.gbase[b], bb = shm.s.base[b];
            for (int j = lane; j < n; j += 64) {
                int dst = gb + j;
                if (dst < CAP1)
                    g1rec[(size_t)b * CAP1 + dst] = shm.s.sorted[bb + j];
            }
        }
    }
}

// ---------------------------------------------------------------------------
// Radix pass 2: within each supergroup, split into its 8 tile regions.
// Grid = NSG * SUB2; per-wave sub-histograms (8-way max contention).
// Writes rec2 = (row << 7) | (col & 127) into brec[tile*CAP ...].
// (round-9 verified)
// ---------------------------------------------------------------------------
__global__ __launch_bounds__(256) void tile_split2_kernel(
    const unsigned int* __restrict__ g1rec, const int* __restrict__ gcur1,
    int* __restrict__ gcursor, unsigned int* __restrict__ brec)
{
    const int sg  = blockIdx.x / SUB2;
    const int sub = blockIdx.x % SUB2;
    int cnt = gcur1[sg];
    if (cnt > CAP1) cnt = CAP1;
    const int s0 = sub * CHUNK2;
    if (s0 >= cnt) return;
    const int csize = min(CHUNK2, cnt - s0);
    const unsigned int* src = g1rec + (size_t)sg * CAP1 + s0;

    __shared__ int hist2[32], cur2[32];
    __shared__ int nb[8], bbase[8], gbase2[8];
    __shared__ unsigned int sorted2[CHUNK2];

    const int t = threadIdx.x;
    const int lane = t & 63;
    const int wid = t >> 6;

    if (t < 32) hist2[t] = 0;
    __syncthreads();

#pragma unroll
    for (int i = 0; i < CHUNK2 / 256; ++i) {
        int idx = i * 256 + t;
        if (idx < csize) {
            unsigned r = src[idx];
            atomicAdd(&hist2[wid * 8 + ((r >> 7) & 7)], 1);
        }
    }
    __syncthreads();

    if (t < 8) {
        int run = 0;
#pragma unroll
        for (int w2 = 0; w2 < 4; ++w2) {
            cur2[w2 * 8 + t] = run;
            run += hist2[w2 * 8 + t];
        }
        nb[t] = run;
    }
    __syncthreads();
    if (t == 0) {
        int run = 0;
#pragma unroll
        for (int b = 0; b < 8; ++b) { bbase[b] = run; run += nb[b]; }
    }
    if (t < 8 && nb[t] > 0)
        gbase2[t] = atomicAdd(&gcursor[sg * 8 + t], nb[t]);
    __syncthreads();

#pragma unroll
    for (int i = 0; i < CHUNK2 / 256; ++i) {
        int idx = i * 256 + t;
        if (idx < csize) {
            unsigned r = src[idx];
            int b = (r >> 7) & 7;
            int pos = atomicAdd(&cur2[wid * 8 + b], 1);
            sorted2[bbase[b] + pos] = ((r >> 10) << 7) | (r & 127u);
        }
    }
    __syncthreads();

    for (int b = wid; b < 8; b += 4) {
        int n = nb[b];
        if (!n) continue;
        int gb = gbase2[b], bb = bbase[b];
        size_t tb = (size_t)(sg * 8 + b) * CAP;
        for (int j = lane; j < n; j += 64) {
            int dst = gb + j;
            if (dst < CAP)
                brec[tb + dst] = sorted2[bb + j];
        }
    }
}

// ---------------------------------------------------------------------------
// Fused per-tile counting-sort + register-accumulate aggregate.
// (round-9 verified structure; 16-deep gather batches)
// ---------------------------------------------------------------------------
__global__ __launch_bounds__(512) void tile_sort_agg_kernel(
    const unsigned int* __restrict__ support_bf,
    const unsigned int* __restrict__ brec,
    const int* __restrict__ gcursor,
    const float* __restrict__ bias,
    float* __restrict__ out)
{
    __shared__ unsigned int recs[CAP];
    __shared__ int srow[CAP];
    __shared__ int hist[128], off[128], cur[128];

    const int tid = threadIdx.x;
    const int lane = tid & 63;
    const int wid = tid >> 6;
    const int node0 = blockIdx.x << 7;

    float accx[16], accy[16];
#pragma unroll
    for (int li = 0; li < 16; ++li) { accx[li] = 0.f; accy[li] = 0.f; }

    int cnt = gcursor[blockIdx.x];
    if (cnt > CAP) cnt = CAP;
    const unsigned int* tb = brec + (size_t)blockIdx.x * CAP;

    if (tid < 128) hist[tid] = 0;
    __syncthreads();

    for (int i = tid; i < cnt; i += 512) {
        unsigned r = tb[i];
        recs[i] = r;
        atomicAdd(&hist[r & 127], 1);
    }
    __syncthreads();

    if (wid == 0) {
        int h0 = hist[2 * lane];
        int h1 = hist[2 * lane + 1];
        int s = h0 + h1;
        int sc = s;
#pragma unroll
        for (int d = 1; d < 64; d <<= 1) {
            int t2 = __shfl_up(sc, d);
            if (lane >= d) sc += t2;
        }
        int ex = sc - s;
        off[2 * lane]     = ex;      cur[2 * lane]     = ex;
        off[2 * lane + 1] = ex + h0; cur[2 * lane + 1] = ex + h0;
    }
    __syncthreads();

    for (int i = tid; i < cnt; i += 512) {
        unsigned r = recs[i];
        int pos = atomicAdd(&cur[r & 127], 1);
        srow[pos] = (int)(r >> 7);
    }
    __syncthreads();

#pragma unroll
    for (int li = 0; li < 16; ++li) {
        const int c = li * 8 + wid;
        int j = off[c];
        const int jend = j + hist[c];
        float ax = accx[li], ay = accy[li];
        for (; j + 15 < jend; j += 16) {
            int r0 = srow[j],      r1 = srow[j + 1];
            int r2 = srow[j + 2],  r3 = srow[j + 3];
            int r4 = srow[j + 4],  r5 = srow[j + 5];
            int r6 = srow[j + 6],  r7 = srow[j + 7];
            int r8 = srow[j + 8],  r9 = srow[j + 9];
            int rA = srow[j + 10], rB = srow[j + 11];
            int rC = srow[j + 12], rD = srow[j + 13];
            int rE = srow[j + 14], rF = srow[j + 15];
            unsigned u0 = support_bf[(size_t)r0 * 64 + lane];
            unsigned u1 = support_bf[(size_t)r1 * 64 + lane];
            unsigned u2 = support_bf[(size_t)r2 * 64 + lane];
            unsigned u3 = support_bf[(size_t)r3 * 64 + lane];
            unsigned u4 = support_bf[(size_t)r4 * 64 + lane];
            unsigned u5 = support_bf[(size_t)r5 * 64 + lane];
            unsigned u6 = support_bf[(size_t)r6 * 64 + lane];
            unsigned u7 = support_bf[(size_t)r7 * 64 + lane];
            unsigned u8 = support_bf[(size_t)r8 * 64 + lane];
            unsigned u9 = support_bf[(size_t)r9 * 64 + lane];
            unsigned uA = support_bf[(size_t)rA * 64 + lane];
            unsigned uB = support_bf[(size_t)rB * 64 + lane];
            unsigned uC = support_bf[(size_t)rC * 64 + lane];
            unsigned uD = support_bf[(size_t)rD * 64 + lane];
            unsigned uE = support_bf[(size_t)rE * 64 + lane];
            unsigned uF = support_bf[(size_t)rF * 64 + lane];
            ax += bf_lo(u0); ay += bf_hi(u0);
            ax += bf_lo(u1); ay += bf_hi(u1);
            ax += bf_lo(u2); ay += bf_hi(u2);
            ax += bf_lo(u3); ay += bf_hi(u3);
            ax += bf_lo(u4); ay += bf_hi(u4);
            ax += bf_lo(u5); ay += bf_hi(u5);
            ax += bf_lo(u6); ay += bf_hi(u6);
            ax += bf_lo(u7); ay += bf_hi(u7);
            ax += bf_lo(u8); ay += bf_hi(u8);
            ax += bf_lo(u9); ay += bf_hi(u9);
            ax += bf_lo(uA); ay += bf_hi(uA);
            ax += bf_lo(uB); ay += bf_hi(uB);
            ax += bf_lo(uC); ay += bf_hi(uC);
            ax += bf_lo(uD); ay += bf_hi(uD);
            ax += bf_lo(uE); ay += bf_hi(uE);
            ax += bf_lo(uF); ay += bf_hi(uF);
        }
        for (; j + 3 < jend; j += 4) {
            int r0 = srow[j],     r1 = srow[j + 1];
            int r2 = srow[j + 2], r3 = srow[j + 3];
            unsigned u0 = support_bf[(size_t)r0 * 64 + lane];
            unsigned u1 = support_bf[(size_t)r1 * 64 + lane];
            unsigned u2 = support_bf[(size_t)r2 * 64 + lane];
            unsigned u3 = support_bf[(size_t)r3 * 64 + lane];
            ax += bf_lo(u0); ay += bf_hi(u0);
            ax += bf_lo(u1); ay += bf_hi(u1);
            ax += bf_lo(u2); ay += bf_hi(u2);
            ax += bf_lo(u3); ay += bf_hi(u3);
        }
        for (; j < jend; ++j) {
            unsigned u0 = support_bf[(size_t)srow[j] * 64 + lane];
            ax += bf_lo(u0); ay += bf_hi(u0);
        }
        accx[li] = ax; accy[li] = ay;
    }

    const int nrows = min(TILE, NUM_NODES - node0);
    float2 bi = *reinterpret_cast<const float2*>(bias + lane * 2);
#pragma unroll
    for (int li = 0; li < 16; ++li) {
        const int c = li * 8 + wid;
        if (c < nrows) {
            const int nd = node0 + c;
            unsigned s = support_bf[(size_t)nd * 64 + lane];
            float2 o = {accx[li] + bf_lo(s) + bi.x,
                        accy[li] + bf_hi(s) + bi.y};
            *reinterpret_cast<float2*>(out + (size_t)nd * OUT_F + lane * 2) = o;
        }
    }
}

extern "C" void kernel_launch(void* const* d_in, const int* in_sizes, int n_in,
                              void* d_out, int out_size, void* d_ws, size_t ws_size,
                              hipStream_t stream) {
    const float* x    = (const float*)d_in[0];
    const float* w    = (const float*)d_in[1];
    const float* bias = (const float*)d_in[2];
    const int*   ei   = (const int*)d_in[3];
    float* out = (float*)d_out;
    const int E = in_sizes[3] / 2;
    const int N = NUM_NODES;

    // Workspace layout (~41.7 MB):
    //   support_bf : N*64 uints (bf16x2)   = 25.6 MB
    //   wt_bf      : 128*256 ushorts       = 64 KB
    //   gcursor    : 1024 ints (per tile)
    //   gcur1      : 128 ints  (per supergroup)   [contiguous w/ gcursor]
    //   g1rec      : NSG*CAP1 uints        = 8.0 MB
    //   brec       : NT*CAP uints          = 8.0 MB
    unsigned int* support_bf = (unsigned int*)d_ws;
    unsigned short* wt_bf = (unsigned short*)(support_bf + (size_t)N * 64);
    int* gcursor = (int*)(wt_bf + 128 * 256);
    int* gcur1   = gcursor + 1024;
    unsigned int* g1rec = (unsigned int*)(gcur1 + 128);
    unsigned int* brec  = g1rec + (size_t)NSG * CAP1;

    const int nG = (N + 127) / 128;              // 782 gemm blocks
    const int nS = (E + CHUNK1 - 1) / CHUNK1;    // 782 split blocks

    // 0. W transpose+convert (2 us) and cursor clear
    convert_wt_kernel<<<128, 256, 0, stream>>>(w, wt_bf);
    hipMemsetAsync(gcursor, 0, (1024 + 128) * sizeof(int), stream);

    // 1. Fused GEMM + radix pass 1 (role-interleaved, data-independent)
    gemm_split_kernel<<<nG + nS, 512, 0, stream>>>(
        x, wt_bf, (unsigned short*)support_bf, ei, E, gcur1, g1rec, nG, nS);

    // 2. Radix pass 2: supergroup -> per-tile regions
    tile_split2_kernel<<<NSG * SUB2, 256, 0, stream>>>(
        g1rec, gcur1, gcursor, brec);

    // 3. Fused per-tile sort + register-accumulate aggregate (16-deep MLP)
    tile_sort_agg_kernel<<<NT, 512, 0, stream>>>(
        support_bf, brec, gcursor, bias, out);
}

// Round 12
// 138.366 us; speedup vs baseline: 1.5088x; 1.2055x over previous
//
#include <hip/hip_runtime.h>

#define NUM_NODES 100000
#define IN_F 256
#define OUT_F 128
#define TILE 128
#define NT ((NUM_NODES + TILE - 1) / TILE)   // 782 tiles of 128 nodes
#define NSG 98               // supergroups of 1024 nodes (8 tiles)
#define CHUNK1 4096
#define CHUNK2 4096
#define CAP1 20480           // per-supergroup capacity (mean 16327, ~32 sigma)
#define SUB2 (CAP1 / CHUNK2) // 5 subchunks per supergroup in pass 2
#define CAP 2560             // per-tile record capacity (mean 2046, 11 sigma)

typedef __attribute__((ext_vector_type(8))) short bf16x8;
typedef __attribute__((ext_vector_type(4))) float f32x4;

__device__ inline unsigned short f2bf(float f) {
    unsigned u = __float_as_uint(f);
    u = (u + 0x7FFFu + ((u >> 16) & 1u)) >> 16;
    return (unsigned short)u;
}
__device__ inline float bf_lo(unsigned int u) { return __uint_as_float(u << 16); }
__device__ inline float bf_hi(unsigned int u) { return __uint_as_float(u & 0xFFFF0000u); }

// ---------------------------------------------------------------------------
// WT[n][k] = bf16(W[k][n])
// ---------------------------------------------------------------------------
__global__ __launch_bounds__(256) void convert_wt_kernel(
    const float* __restrict__ w, unsigned short* __restrict__ wt)
{
    int g = blockIdx.x * 256 + threadIdx.x;      // 0..32767 = k*128+n
    int k = g >> 7, n = g & 127;
    wt[n * 256 + k] = f2bf(w[g]);
}

// ---------------------------------------------------------------------------
// support = bf16(X @ W) via MFMA. 8 waves x 16-row strips = 128 rows/block.
// (round-4..9 verified; ~its memory floor ~20 us)
// ---------------------------------------------------------------------------
__global__ __launch_bounds__(512) void gemm_mfma_kernel(
    const float* __restrict__ x, const unsigned short* __restrict__ wt,
    unsigned short* __restrict__ support_h)
{
    __shared__ unsigned short WT[128][264];

    const int tid = threadIdx.x;
    const uint4* src = reinterpret_cast<const uint4*>(wt);
#pragma unroll
    for (int i = 0; i < 8; ++i) {
        int j = tid + i * 512;
        int r = j >> 5;
        int c = (j & 31) << 3;
        *reinterpret_cast<uint4*>(&WT[r][c]) = src[j];
    }
    __syncthreads();

    const int wave = tid >> 6;
    const int lane = tid & 63;
    const int q = lane >> 4;
    const int r16 = lane & 15;
    const int strip_row = blockIdx.x * 128 + wave * 16;

    int arow = strip_row + r16;
    if (arow >= NUM_NODES) arow = NUM_NODES - 1;
    const float* xrow = x + (size_t)arow * IN_F + q * 8;

    f32x4 acc[8];
#pragma unroll
    for (int n = 0; n < 8; ++n) acc[n] = (f32x4){0.f, 0.f, 0.f, 0.f};

#pragma unroll
    for (int half = 0; half < 2; ++half) {
        float4 a[8];
#pragma unroll
        for (int g = 0; g < 4; ++g) {
            const float* p = xrow + half * 128 + g * 32;
            a[g * 2]     = *reinterpret_cast<const float4*>(p);
            a[g * 2 + 1] = *reinterpret_cast<const float4*>(p + 4);
        }
#pragma unroll
        for (int g = 0; g < 4; ++g) {
            const int k0 = half * 128 + g * 32;
            bf16x8 af;
            af[0] = (short)f2bf(a[g * 2].x);
            af[1] = (short)f2bf(a[g * 2].y);
            af[2] = (short)f2bf(a[g * 2].z);
            af[3] = (short)f2bf(a[g * 2].w);
            af[4] = (short)f2bf(a[g * 2 + 1].x);
            af[5] = (short)f2bf(a[g * 2 + 1].y);
            af[6] = (short)f2bf(a[g * 2 + 1].z);
            af[7] = (short)f2bf(a[g * 2 + 1].w);
#pragma unroll
            for (int n = 0; n < 8; ++n) {
                bf16x8 bfr = *reinterpret_cast<const bf16x8*>(
                    &WT[n * 16 + r16][k0 + q * 8]);
                acc[n] = __builtin_amdgcn_mfma_f32_16x16x32_bf16(
                    af, bfr, acc[n], 0, 0, 0);
            }
        }
    }

#pragma unroll
    for (int n = 0; n < 8; ++n) {
#pragma unroll
        for (int rr = 0; rr < 4; ++rr) {
            int grow = strip_row + q * 4 + rr;
            if (grow < NUM_NODES)
                support_h[(size_t)grow * OUT_F + n * 16 + r16] = f2bf(acc[n][rr]);
        }
    }
}

// ---------------------------------------------------------------------------
// Radix pass 1: split edges into 98 supergroup regions (1024 dest nodes).
// 512 threads, chunk 4096; wave-0 shfl scan (2 barriers); copy-out spread
// over 8 waves (12-13 buckets/wave). rec = (row << 10) | (col & 1023).
// ---------------------------------------------------------------------------
__global__ __launch_bounds__(512) void sg_split_kernel(
    const int* __restrict__ ei, int E, int* __restrict__ gcur1,
    unsigned int* __restrict__ g1rec)
{
    __shared__ int hist[128], base[128], gbase[128], cur[128];
    __shared__ unsigned int sorted[CHUNK1];
    const int t = threadIdx.x;
    const int lane = t & 63;
    const int wid = t >> 6;
    const int e0 = blockIdx.x * CHUNK1;

    if (t < 128) hist[t] = 0;
    __syncthreads();

#pragma unroll
    for (int i = 0; i < CHUNK1 / 512; ++i) {
        int e = e0 + i * 512 + t;
        if (e < E) atomicAdd(&hist[ei[E + e] >> 10], 1);
    }
    __syncthreads();

    // wave-0 shfl exclusive scan of hist[128] + global reservations
    if (wid == 0) {
        int h0 = hist[2 * lane];
        int h1 = hist[2 * lane + 1];
        int s = h0 + h1;
        int sc = s;
#pragma unroll
        for (int d = 1; d < 64; d <<= 1) {
            int t2 = __shfl_up(sc, d);
            if (lane >= d) sc += t2;
        }
        int ex = sc - s;
        base[2 * lane]     = ex;      cur[2 * lane]     = ex;
        base[2 * lane + 1] = ex + h0; cur[2 * lane + 1] = ex + h0;
        gbase[2 * lane]     = h0 ? atomicAdd(&gcur1[2 * lane], h0) : 0;
        gbase[2 * lane + 1] = h1 ? atomicAdd(&gcur1[2 * lane + 1], h1) : 0;
    }
    __syncthreads();

#pragma unroll
    for (int i = 0; i < CHUNK1 / 512; ++i) {
        int e = e0 + i * 512 + t;
        if (e < E) {
            int row = ei[e], col = ei[E + e];
            int b = col >> 10;
            int pos = atomicAdd(&cur[b], 1);
            sorted[pos] = ((unsigned)row << 10) | (unsigned)(col & 1023);
        }
    }
    __syncthreads();

    for (int b = wid; b < NSG; b += 8) {
        int n = hist[b];
        if (!n) continue;
        int gb = gbase[b], bb = base[b];
        for (int j = lane; j < n; j += 64) {
            int dst = gb + j;
            if (dst < CAP1)
                g1rec[(size_t)b * CAP1 + dst] = sorted[bb + j];
        }
    }
}

// ---------------------------------------------------------------------------
// Radix pass 2: within each supergroup, split into its 8 tile regions.
// 512 threads; per-wave sub-histograms (8 waves x 8 buckets); copy-out is
// exactly 1 bucket per wave (~512-record coalesced runs).
// rec2 = (row << 7) | (col & 127) into brec[tile*CAP ...].
// ---------------------------------------------------------------------------
__global__ __launch_bounds__(512) void tile_split2_kernel(
    const unsigned int* __restrict__ g1rec, const int* __restrict__ gcur1,
    int* __restrict__ gcursor, unsigned int* __restrict__ brec)
{
    const int sg  = blockIdx.x / SUB2;
    const int sub = blockIdx.x % SUB2;
    int cnt = gcur1[sg];
    if (cnt > CAP1) cnt = CAP1;
    const int s0 = sub * CHUNK2;
    if (s0 >= cnt) return;                        // uniform exit
    const int csize = min(CHUNK2, cnt - s0);
    const unsigned int* src = g1rec + (size_t)sg * CAP1 + s0;

    __shared__ int hist2[64], cur2[64];           // [wave][bucket]
    __shared__ int nb[8], bbase[8], gbase2[8];
    __shared__ unsigned int sorted2[CHUNK2];

    const int t = threadIdx.x;
    const int lane = t & 63;
    const int wid = t >> 6;

    if (t < 64) hist2[t] = 0;
    __syncthreads();

#pragma unroll
    for (int i = 0; i < CHUNK2 / 512; ++i) {
        int idx = i * 512 + t;
        if (idx < csize) {
            unsigned r = src[idx];
            atomicAdd(&hist2[wid * 8 + ((r >> 7) & 7)], 1);
        }
    }
    __syncthreads();

    if (t < 8) {        // in-bucket offsets per wave + bucket totals
        int run = 0;
#pragma unroll
        for (int w2 = 0; w2 < 8; ++w2) {
            cur2[w2 * 8 + t] = run;
            run += hist2[w2 * 8 + t];
        }
        nb[t] = run;
    }
    __syncthreads();
    if (t == 0) {
        int run = 0;
#pragma unroll
        for (int b = 0; b < 8; ++b) { bbase[b] = run; run += nb[b]; }
    }
    if (t < 8 && nb[t] > 0)
        gbase2[t] = atomicAdd(&gcursor[sg * 8 + t], nb[t]);
    __syncthreads();

#pragma unroll
    for (int i = 0; i < CHUNK2 / 512; ++i) {
        int idx = i * 512 + t;
        if (idx < csize) {
            unsigned r = src[idx];
            int b = (r >> 7) & 7;
            int pos = atomicAdd(&cur2[wid * 8 + b], 1);
            sorted2[bbase[b] + pos] = ((r >> 10) << 7) | (r & 127u);
        }
    }
    __syncthreads();

    {   // copy-out: wave w handles bucket w
        int b = wid;
        int n = nb[b];
        if (n) {
            int gb = gbase2[b], bb = bbase[b];
            size_t tb = (size_t)(sg * 8 + b) * CAP;
            for (int j = lane; j < n; j += 64) {
                int dst = gb + j;
                if (dst < CAP)
                    brec[tb + dst] = sorted2[bb + j];
            }
        }
    }
}

// ---------------------------------------------------------------------------
// Fused per-tile counting-sort + register-accumulate aggregate.
// (round-9 verified verbatim: 8-deep gather batches, VGPR 32, occ ~54%)
// ---------------------------------------------------------------------------
__global__ __launch_bounds__(512) void tile_sort_agg_kernel(
    const unsigned int* __restrict__ support_bf,
    const unsigned int* __restrict__ brec,
    const int* __restrict__ gcursor,
    const float* __restrict__ bias,
    float* __restrict__ out)
{
    __shared__ unsigned int recs[CAP];
    __shared__ int srow[CAP];
    __shared__ int hist[128], off[128], cur[128];

    const int tid = threadIdx.x;
    const int lane = tid & 63;
    const int wid = tid >> 6;
    const int node0 = blockIdx.x << 7;

    float accx[16], accy[16];
#pragma unroll
    for (int li = 0; li < 16; ++li) { accx[li] = 0.f; accy[li] = 0.f; }

    int cnt = gcursor[blockIdx.x];
    if (cnt > CAP) cnt = CAP;
    const unsigned int* tb = brec + (size_t)blockIdx.x * CAP;

    if (tid < 128) hist[tid] = 0;
    __syncthreads();

    for (int i = tid; i < cnt; i += 512) {
        unsigned r = tb[i];
        recs[i] = r;
        atomicAdd(&hist[r & 127], 1);
    }
    __syncthreads();

    if (wid == 0) {
        int h0 = hist[2 * lane];
        int h1 = hist[2 * lane + 1];
        int s = h0 + h1;
        int sc = s;
#pragma unroll
        for (int d = 1; d < 64; d <<= 1) {
            int t2 = __shfl_up(sc, d);
            if (lane >= d) sc += t2;
        }
        int ex = sc - s;
        off[2 * lane]     = ex;      cur[2 * lane]     = ex;
        off[2 * lane + 1] = ex + h0; cur[2 * lane + 1] = ex + h0;
    }
    __syncthreads();

    for (int i = tid; i < cnt; i += 512) {
        unsigned r = recs[i];
        int pos = atomicAdd(&cur[r & 127], 1);
        srow[pos] = (int)(r >> 7);
    }
    __syncthreads();

#pragma unroll
    for (int li = 0; li < 16; ++li) {
        const int c = li * 8 + wid;
        int j = off[c];
        const int jend = j + hist[c];
        float ax = accx[li], ay = accy[li];
        for (; j + 7 < jend; j += 8) {
            int r0 = srow[j],     r1 = srow[j + 1];
            int r2 = srow[j + 2], r3 = srow[j + 3];
            int r4 = srow[j + 4], r5 = srow[j + 5];
            int r6 = srow[j + 6], r7 = srow[j + 7];
            unsigned u0 = support_bf[(size_t)r0 * 64 + lane];
            unsigned u1 = support_bf[(size_t)r1 * 64 + lane];
            unsigned u2 = support_bf[(size_t)r2 * 64 + lane];
            unsigned u3 = support_bf[(size_t)r3 * 64 + lane];
            unsigned u4 = support_bf[(size_t)r4 * 64 + lane];
            unsigned u5 = support_bf[(size_t)r5 * 64 + lane];
            unsigned u6 = support_bf[(size_t)r6 * 64 + lane];
            unsigned u7 = support_bf[(size_t)r7 * 64 + lane];
            ax += bf_lo(u0); ay += bf_hi(u0);
            ax += bf_lo(u1); ay += bf_hi(u1);
            ax += bf_lo(u2); ay += bf_hi(u2);
            ax += bf_lo(u3); ay += bf_hi(u3);
            ax += bf_lo(u4); ay += bf_hi(u4);
            ax += bf_lo(u5); ay += bf_hi(u5);
            ax += bf_lo(u6); ay += bf_hi(u6);
            ax += bf_lo(u7); ay += bf_hi(u7);
        }
        for (; j + 3 < jend; j += 4) {
            int r0 = srow[j],     r1 = srow[j + 1];
            int r2 = srow[j + 2], r3 = srow[j + 3];
            unsigned u0 = support_bf[(size_t)r0 * 64 + lane];
            unsigned u1 = support_bf[(size_t)r1 * 64 + lane];
            unsigned u2 = support_bf[(size_t)r2 * 64 + lane];
            unsigned u3 = support_bf[(size_t)r3 * 64 + lane];
            ax += bf_lo(u0); ay += bf_hi(u0);
            ax += bf_lo(u1); ay += bf_hi(u1);
            ax += bf_lo(u2); ay += bf_hi(u2);
            ax += bf_lo(u3); ay += bf_hi(u3);
        }
        for (; j < jend; ++j) {
            unsigned u0 = support_bf[(size_t)srow[j] * 64 + lane];
            ax += bf_lo(u0); ay += bf_hi(u0);
        }
        accx[li] = ax; accy[li] = ay;
    }

    const int nrows = min(TILE, NUM_NODES - node0);
    float2 bi = *reinterpret_cast<const float2*>(bias + lane * 2);
#pragma unroll
    for (int li = 0; li < 16; ++li) {
        const int c = li * 8 + wid;
        if (c < nrows) {
            const int nd = node0 + c;
            unsigned s = support_bf[(size_t)nd * 64 + lane];
            float2 o = {accx[li] + bf_lo(s) + bi.x,
                        accy[li] + bf_hi(s) + bi.y};
            *reinterpret_cast<float2*>(out + (size_t)nd * OUT_F + lane * 2) = o;
        }
    }
}

extern "C" void kernel_launch(void* const* d_in, const int* in_sizes, int n_in,
                              void* d_out, int out_size, void* d_ws, size_t ws_size,
                              hipStream_t stream) {
    const float* x    = (const float*)d_in[0];
    const float* w    = (const float*)d_in[1];
    const float* bias = (const float*)d_in[2];
    const int*   ei   = (const int*)d_in[3];
    float* out = (float*)d_out;
    const int E = in_sizes[3] / 2;
    const int N = NUM_NODES;

    // Workspace layout (~41.7 MB):
    //   support_bf : N*64 uints (bf16x2)   = 25.6 MB
    //   wt_bf      : 128*256 ushorts       = 64 KB
    //   gcursor    : 1024 ints (per tile)
    //   gcur1      : 128 ints  (per supergroup)
    //   g1rec      : NSG*CAP1 uints        = 8.0 MB
    //   brec       : NT*CAP uints          = 8.0 MB
    unsigned int* support_bf = (unsigned int*)d_ws;
    unsigned short* wt_bf = (unsigned short*)(support_bf + (size_t)N * 64);
    int* gcursor = (int*)(wt_bf + 128 * 256);
    int* gcur1   = gcursor + 1024;
    unsigned int* g1rec = (unsigned int*)(gcur1 + 128);
    unsigned int* brec  = g1rec + (size_t)NSG * CAP1;

    // 0. W transpose+convert and cursor clear
    convert_wt_kernel<<<128, 256, 0, stream>>>(w, wt_bf);
    hipMemsetAsync(gcursor, 0, (1024 + 128) * sizeof(int), stream);

    // 1. GEMM: support = bf16(X @ W) via MFMA
    gemm_mfma_kernel<<<(N + 127) / 128, 512, 0, stream>>>(
        x, wt_bf, (unsigned short*)support_bf);

    // 2. Two-level radix split by destination (supergroup, then tile)
    sg_split_kernel<<<(E + CHUNK1 - 1) / CHUNK1, 512, 0, stream>>>(
        ei, E, gcur1, g1rec);
    tile_split2_kernel<<<NSG * SUB2, 512, 0, stream>>>(
        g1rec, gcur1, gcursor, brec);

    // 3. Fused per-tile sort + register-accumulate aggregate (8-deep MLP)
    tile_sort_agg_kernel<<<NT, 512, 0, stream>>>(
        support_bf, brec, gcursor, bias, out);
}

// Round 13
// 128.580 us; speedup vs baseline: 1.6236x; 1.0761x over previous
//
#include <hip/hip_runtime.h>

#define NUM_NODES 100000
#define IN_F 256
#define OUT_F 128
#define TILE 128
#define NT ((NUM_NODES + TILE - 1) / TILE)   // 782 tiles of 128 nodes
#define CHUNKD 8192          // edges per split block
#define CAP 2560             // per-tile record capacity (mean 2046, 11 sigma)

typedef __attribute__((ext_vector_type(8))) short bf16x8;
typedef __attribute__((ext_vector_type(4))) float f32x4;

__device__ inline unsigned short f2bf(float f) {
    unsigned u = __float_as_uint(f);
    u = (u + 0x7FFFu + ((u >> 16) & 1u)) >> 16;
    return (unsigned short)u;
}
__device__ inline float bf_lo(unsigned int u) { return __uint_as_float(u << 16); }
__device__ inline float bf_hi(unsigned int u) { return __uint_as_float(u & 0xFFFF0000u); }

// ---------------------------------------------------------------------------
// WT[n][k] = bf16(W[k][n])
// ---------------------------------------------------------------------------
__global__ __launch_bounds__(256) void convert_wt_kernel(
    const float* __restrict__ w, unsigned short* __restrict__ wt)
{
    int g = blockIdx.x * 256 + threadIdx.x;      // 0..32767 = k*128+n
    int k = g >> 7, n = g & 127;
    wt[n * 256 + k] = f2bf(w[g]);
}

// ---------------------------------------------------------------------------
// support = bf16(X @ W) via MFMA. 8 waves x 16-row strips = 128 rows/block.
// (verified; ~its 20 us HBM floor)
// ---------------------------------------------------------------------------
__global__ __launch_bounds__(512) void gemm_mfma_kernel(
    const float* __restrict__ x, const unsigned short* __restrict__ wt,
    unsigned short* __restrict__ support_h)
{
    __shared__ unsigned short WT[128][264];

    const int tid = threadIdx.x;
    const uint4* src = reinterpret_cast<const uint4*>(wt);
#pragma unroll
    for (int i = 0; i < 8; ++i) {
        int j = tid + i * 512;
        int r = j >> 5;
        int c = (j & 31) << 3;
        *reinterpret_cast<uint4*>(&WT[r][c]) = src[j];
    }
    __syncthreads();

    const int wave = tid >> 6;
    const int lane = tid & 63;
    const int q = lane >> 4;
    const int r16 = lane & 15;
    const int strip_row = blockIdx.x * 128 + wave * 16;

    int arow = strip_row + r16;
    if (arow >= NUM_NODES) arow = NUM_NODES - 1;
    const float* xrow = x + (size_t)arow * IN_F + q * 8;

    f32x4 acc[8];
#pragma unroll
    for (int n = 0; n < 8; ++n) acc[n] = (f32x4){0.f, 0.f, 0.f, 0.f};

#pragma unroll
    for (int half = 0; half < 2; ++half) {
        float4 a[8];
#pragma unroll
        for (int g = 0; g < 4; ++g) {
            const float* p = xrow + half * 128 + g * 32;
            a[g * 2]     = *reinterpret_cast<const float4*>(p);
            a[g * 2 + 1] = *reinterpret_cast<const float4*>(p + 4);
        }
#pragma unroll
        for (int g = 0; g < 4; ++g) {
            const int k0 = half * 128 + g * 32;
            bf16x8 af;
            af[0] = (short)f2bf(a[g * 2].x);
            af[1] = (short)f2bf(a[g * 2].y);
            af[2] = (short)f2bf(a[g * 2].z);
            af[3] = (short)f2bf(a[g * 2].w);
            af[4] = (short)f2bf(a[g * 2 + 1].x);
            af[5] = (short)f2bf(a[g * 2 + 1].y);
            af[6] = (short)f2bf(a[g * 2 + 1].z);
            af[7] = (short)f2bf(a[g * 2 + 1].w);
#pragma unroll
            for (int n = 0; n < 8; ++n) {
                bf16x8 bfr = *reinterpret_cast<const bf16x8*>(
                    &WT[n * 16 + r16][k0 + q * 8]);
                acc[n] = __builtin_amdgcn_mfma_f32_16x16x32_bf16(
                    af, bfr, acc[n], 0, 0, 0);
            }
        }
    }

#pragma unroll
    for (int n = 0; n < 8; ++n) {
#pragma unroll
        for (int rr = 0; rr < 4; ++rr) {
            int grow = strip_row + q * 4 + rr;
            if (grow < NUM_NODES)
                support_h[(size_t)grow * OUT_F + n * 16 + r16] = f2bf(acc[n][rr]);
        }
    }
}

// ---------------------------------------------------------------------------
// Single-pass direct tile split. Per block: 8192 edges, LDS histogram over
// 782 tile buckets, ONE global atomicAdd per non-empty bucket to reserve a
// contiguous range, then direct scattered writes at LDS-ranked positions.
// Per-block per-bucket runs (~21 records = 84 B) are contiguous and written
// within one block's execution window -> L2 write-combines them.
// rec = (row << 7) | (col & 127). No record staging, no scan, no 2nd pass.
// ---------------------------------------------------------------------------
__global__ __launch_bounds__(512) void tile_split_direct_kernel(
    const int* __restrict__ ei, int E, int* __restrict__ gcursor,
    unsigned int* __restrict__ brec)
{
    __shared__ int hist[NT];
    __shared__ int cur[NT];
    const int t = threadIdx.x;
    const int e0 = blockIdx.x * CHUNKD;
    const int n = min(CHUNKD, E - e0);

    for (int i = t; i < NT; i += 512) hist[i] = 0;
    __syncthreads();

    for (int i = t; i < n; i += 512)
        atomicAdd(&hist[ei[E + e0 + i] >> 7], 1);
    __syncthreads();

    for (int b = t; b < NT; b += 512) {
        int h = hist[b];
        cur[b] = h ? atomicAdd(&gcursor[b], h) : 0;   // global base directly
    }
    __syncthreads();

    for (int i = t; i < n; i += 512) {
        int row = ei[e0 + i], col = ei[E + e0 + i];
        int b = col >> 7;
        int pos = atomicAdd(&cur[b], 1);
        if (pos < CAP)
            brec[(size_t)b * CAP + pos] =
                ((unsigned)row << 7) | (unsigned)(col & 127);
    }
}

// ---------------------------------------------------------------------------
// Fused per-tile counting-sort + register-accumulate aggregate.
// (verified verbatim: 8-deep gather batches, VGPR 32, occ ~54%, ~68 us)
// ---------------------------------------------------------------------------
__global__ __launch_bounds__(512) void tile_sort_agg_kernel(
    const unsigned int* __restrict__ support_bf,
    const unsigned int* __restrict__ brec,
    const int* __restrict__ gcursor,
    const float* __restrict__ bias,
    float* __restrict__ out)
{
    __shared__ unsigned int recs[CAP];
    __shared__ int srow[CAP];
    __shared__ int hist[128], off[128], cur[128];

    const int tid = threadIdx.x;
    const int lane = tid & 63;
    const int wid = tid >> 6;
    const int node0 = blockIdx.x << 7;

    float accx[16], accy[16];
#pragma unroll
    for (int li = 0; li < 16; ++li) { accx[li] = 0.f; accy[li] = 0.f; }

    int cnt = gcursor[blockIdx.x];
    if (cnt > CAP) cnt = CAP;
    const unsigned int* tb = brec + (size_t)blockIdx.x * CAP;

    if (tid < 128) hist[tid] = 0;
    __syncthreads();

    for (int i = tid; i < cnt; i += 512) {
        unsigned r = tb[i];
        recs[i] = r;
        atomicAdd(&hist[r & 127], 1);
    }
    __syncthreads();

    if (wid == 0) {
        int h0 = hist[2 * lane];
        int h1 = hist[2 * lane + 1];
        int s = h0 + h1;
        int sc = s;
#pragma unroll
        for (int d = 1; d < 64; d <<= 1) {
            int t2 = __shfl_up(sc, d);
            if (lane >= d) sc += t2;
        }
        int ex = sc - s;
        off[2 * lane]     = ex;      cur[2 * lane]     = ex;
        off[2 * lane + 1] = ex + h0; cur[2 * lane + 1] = ex + h0;
    }
    __syncthreads();

    for (int i = tid; i < cnt; i += 512) {
        unsigned r = recs[i];
        int pos = atomicAdd(&cur[r & 127], 1);
        srow[pos] = (int)(r >> 7);
    }
    __syncthreads();

#pragma unroll
    for (int li = 0; li < 16; ++li) {
        const int c = li * 8 + wid;
        int j = off[c];
        const int jend = j + hist[c];
        float ax = accx[li], ay = accy[li];
        for (; j + 7 < jend; j += 8) {
            int r0 = srow[j],     r1 = srow[j + 1];
            int r2 = srow[j + 2], r3 = srow[j + 3];
            int r4 = srow[j + 4], r5 = srow[j + 5];
            int r6 = srow[j + 6], r7 = srow[j + 7];
            unsigned u0 = support_bf[(size_t)r0 * 64 + lane];
            unsigned u1 = support_bf[(size_t)r1 * 64 + lane];
            unsigned u2 = support_bf[(size_t)r2 * 64 + lane];
            unsigned u3 = support_bf[(size_t)r3 * 64 + lane];
            unsigned u4 = support_bf[(size_t)r4 * 64 + lane];
            unsigned u5 = support_bf[(size_t)r5 * 64 + lane];
            unsigned u6 = support_bf[(size_t)r6 * 64 + lane];
            unsigned u7 = support_bf[(size_t)r7 * 64 + lane];
            ax += bf_lo(u0); ay += bf_hi(u0);
            ax += bf_lo(u1); ay += bf_hi(u1);
            ax += bf_lo(u2); ay += bf_hi(u2);
            ax += bf_lo(u3); ay += bf_hi(u3);
            ax += bf_lo(u4); ay += bf_hi(u4);
            ax += bf_lo(u5); ay += bf_hi(u5);
            ax += bf_lo(u6); ay += bf_hi(u6);
            ax += bf_lo(u7); ay += bf_hi(u7);
        }
        for (; j + 3 < jend; j += 4) {
            int r0 = srow[j],     r1 = srow[j + 1];
            int r2 = srow[j + 2], r3 = srow[j + 3];
            unsigned u0 = support_bf[(size_t)r0 * 64 + lane];
            unsigned u1 = support_bf[(size_t)r1 * 64 + lane];
            unsigned u2 = support_bf[(size_t)r2 * 64 + lane];
            unsigned u3 = support_bf[(size_t)r3 * 64 + lane];
            ax += bf_lo(u0); ay += bf_hi(u0);
            ax += bf_lo(u1); ay += bf_hi(u1);
            ax += bf_lo(u2); ay += bf_hi(u2);
            ax += bf_lo(u3); ay += bf_hi(u3);
        }
        for (; j < jend; ++j) {
            unsigned u0 = support_bf[(size_t)srow[j] * 64 + lane];
            ax += bf_lo(u0); ay += bf_hi(u0);
        }
        accx[li] = ax; accy[li] = ay;
    }

    const int nrows = min(TILE, NUM_NODES - node0);
    float2 bi = *reinterpret_cast<const float2*>(bias + lane * 2);
#pragma unroll
    for (int li = 0; li < 16; ++li) {
        const int c = li * 8 + wid;
        if (c < nrows) {
            const int nd = node0 + c;
            unsigned s = support_bf[(size_t)nd * 64 + lane];
            float2 o = {accx[li] + bf_lo(s) + bi.x,
                        accy[li] + bf_hi(s) + bi.y};
            *reinterpret_cast<float2*>(out + (size_t)nd * OUT_F + lane * 2) = o;
        }
    }
}

extern "C" void kernel_launch(void* const* d_in, const int* in_sizes, int n_in,
                              void* d_out, int out_size, void* d_ws, size_t ws_size,
                              hipStream_t stream) {
    const float* x    = (const float*)d_in[0];
    const float* w    = (const float*)d_in[1];
    const float* bias = (const float*)d_in[2];
    const int*   ei   = (const int*)d_in[3];
    float* out = (float*)d_out;
    const int E = in_sizes[3] / 2;
    const int N = NUM_NODES;

    // Workspace layout (~33.7 MB):
    //   support_bf : N*64 uints (bf16x2)   = 25.6 MB
    //   wt_bf      : 128*256 ushorts       = 64 KB
    //   gcursor    : 1024 ints (per tile)
    //   brec       : NT*CAP uints          = 8.0 MB
    unsigned int* support_bf = (unsigned int*)d_ws;
    unsigned short* wt_bf = (unsigned short*)(support_bf + (size_t)N * 64);
    int* gcursor = (int*)(wt_bf + 128 * 256);
    unsigned int* brec = (unsigned int*)(gcursor + 1024);

    // 0. W transpose+convert and cursor clear
    convert_wt_kernel<<<128, 256, 0, stream>>>(w, wt_bf);
    hipMemsetAsync(gcursor, 0, 1024 * sizeof(int), stream);

    // 1. GEMM: support = bf16(X @ W) via MFMA
    gemm_mfma_kernel<<<(N + 127) / 128, 512, 0, stream>>>(
        x, wt_bf, (unsigned short*)support_bf);

    // 2. Single-pass direct tile split (no staging, no scan, no 2nd pass)
    tile_split_direct_kernel<<<(E + CHUNKD - 1) / CHUNKD, 512, 0, stream>>>(
        ei, E, gcursor, brec);

    // 3. Fused per-tile sort + register-accumulate aggregate (8-deep MLP)
    tile_sort_agg_kernel<<<NT, 512, 0, stream>>>(
        support_bf, brec, gcursor, bias, out);
}